// Round 8
// baseline (139.300 us; speedup 1.0000x reference)
//
#include <hip/hip_runtime.h>
#include <hip/hip_cooperative_groups.h>

namespace cg = cooperative_groups;

#define KAPPA 0.276f
#define NTRI 8256        // 128*129/2 packed floats per batch
#define BATCH 1024
#define SCALE (1.0f / (128.0f * 1024.0f))   // /trace2(=128), /B for mean

__global__ __launch_bounds__(256) void trace_kernel(const float* __restrict__ net_out,
                                                    const float* __restrict__ U1,
                                                    float* __restrict__ ws,
                                                    float* __restrict__ out) {
    const int b   = blockIdx.x;               // one block per batch
    const int tid = threadIdx.x;
    const int w   = tid >> 6;                 // wave 0..3
    const int l   = tid & 63;                 // lane owns elements k=l and k=l+64 of each row

    const float* __restrict__ X = net_out + (size_t)b * NTRI;
    const float* __restrict__ U = U1 + (size_t)b * 128;

    // loop-invariant per-lane element offsets within a row
    const int kxl = l;
    const int kal = l + 16;
    const int kbl = (l & 0x70) | ((l + 2) & 15);
    const int kxh = l + 64;
    const int kah = (l + 80) & 127;
    const int kbh = ((l + 64) & 0x70) | ((l + 66) & 15);

    float sq = 0.f, hAl = 0.f, hBl = 0.f, hAh = 0.f, hBh = 0.f;

    // wave w handles row classes r = w and r = w+4 (rows r, r+8, ..., r+120)
    #pragma unroll
    for (int c = 0; c < 2; ++c) {
        const int r = w + (c << 2);
        // ---- rows i = r .. r+56 : only low half valid (k <= i < 64) ----
        {
            int i = r;
            int o = (r * (r + 1)) >> 1;
            #pragma unroll 4
            for (int t = 0; t < 8; ++t) {
                const float* __restrict__ R = X + o;
                float x  = R[kxl];
                float a  = R[kal];
                float bb = R[kbl];
                x  = (kxl <= i) ? x  : 0.f;
                a  = (kal <= i) ? a  : 0.f;
                bb = (kbl <= i) ? bb : 0.f;
                sq  = fmaf(x, x,  sq);
                hAl = fmaf(x, a,  hAl);
                hBl = fmaf(x, bb, hBl);
                o += (i << 3) + 36;
                i += 8;
            }
        }
        // ---- rows i = r+64 .. r+120 : both halves ----
        {
            int i = r + 64;
            int o = (i * (i + 1)) >> 1;
            #pragma unroll 4
            for (int t = 0; t < 8; ++t) {
                const float* __restrict__ R = X + o;
                float x  = R[kxl];           // k=l <= 63 < i: always valid
                float a  = R[kal];
                float bb = R[kbl];
                a = (kal <= i) ? a : 0.f;    // kbl <= 63 < i: always valid
                sq  = fmaf(x, x,  sq);
                hAl = fmaf(x, a,  hAl);
                hBl = fmaf(x, bb, hBl);

                float xh = R[kxh];
                float ah = R[kah];
                float bh = R[kbh];
                xh = (kxh <= i) ? xh : 0.f;
                ah = (kah <= i) ? ah : 0.f;
                bh = (kbh <= i) ? bh : 0.f;
                sq  = fmaf(xh, xh, sq);
                hAh = fmaf(xh, ah, hAh);
                hBh = fmaf(xh, bh, hBh);

                o += (i << 3) + 36;
                i += 8;
            }
        }
    }

    // per-lane coefficients (site of element k is k>>1); HW cos, rel err ~1e-5
    const float m2k = -2.0f * KAPPA;
    const float cAl = m2k * __cosf(U[(l >> 1)]);
    const float cAh = m2k * __cosf(U[32 + (l >> 1)]);
    const float cBl = m2k * __cosf(U[64 + (l >> 1)]);
    const float cBh = m2k * __cosf(U[96 + (l >> 1)]);

    float val = sq + cAl * hAl + cAh * hAh + cBl * hBl + cBh * hBh;

    // wave reduce
    #pragma unroll
    for (int off = 32; off > 0; off >>= 1)
        val += __shfl_down(val, off, 64);

    __shared__ float red[4];
    if (l == 0) red[w] = val;
    __syncthreads();
    if (tid == 0)
        ws[b] = red[0] + red[1] + red[2] + red[3];   // plain store; grid.sync fences

    cg::this_grid().sync();

    // block 0 reduces 1024 partials in fixed order (deterministic)
    if (b == 0) {
        float v = ws[tid] + ws[tid + 256] + ws[tid + 512] + ws[tid + 768];
        #pragma unroll
        for (int off = 32; off > 0; off >>= 1)
            v += __shfl_down(v, off, 64);
        if (l == 0) red[w] = v;       // safe: grid.sync() block-synchronized us
        __syncthreads();
        if (tid == 0)
            out[0] = (red[0] + red[1] + red[2] + red[3]) * SCALE;
    }
}

extern "C" void kernel_launch(void* const* d_in, const int* in_sizes, int n_in,
                              void* d_out, int out_size, void* d_ws, size_t ws_size,
                              hipStream_t stream) {
    const float* net_out = (const float*)d_in[0];  // (1024, 8256) fp32
    const float* U1      = (const float*)d_in[1];  // (1024, 2, 8, 8) fp32
    float* out = (float*)d_out;                    // scalar fp32
    float* ws  = (float*)d_ws;                     // >= 1024 floats

    void* args[] = { (void*)&net_out, (void*)&U1, (void*)&ws, (void*)&out };
    hipLaunchCooperativeKernel((const void*)trace_kernel,
                               dim3(BATCH), dim3(256), args, 0, stream);
}

// Round 9
// 40.928 us; speedup vs baseline: 3.4035x; 3.4035x over previous
//
#include <hip/hip_runtime.h>

#define KAPPA 0.276f
#define NTRI 8256        // 128*129/2 packed floats per batch
#define BATCH 1024
#define NBLK 2048        // 2 blocks per batch (row classes mod 8)
#define SCALE (1.0f / (128.0f * 1024.0f))   // /trace2(=128), /B for mean

__global__ __launch_bounds__(256) void trace_kernel(const float* __restrict__ net_out,
                                                    const float* __restrict__ U1,
                                                    float* __restrict__ out) {
    const int bid = blockIdx.x;
    const int b   = bid >> 1;
    const int tid = threadIdx.x;
    const int w   = tid >> 6;                 // wave 0..3
    const int l   = tid & 63;                 // lane owns elements k=l and k=l+64 of each row
    const int r   = ((bid & 1) << 2) + w;     // row class 0..7: rows r, r+8, ..., r+120

    const float* __restrict__ X = net_out + (size_t)b * NTRI;
    const float* __restrict__ U = U1 + (size_t)b * 128;

    // loop-invariant per-lane element offsets within a row
    const int kxl = l;
    const int kal = l + 16;
    const int kbl = (l & 0x70) | ((l + 2) & 15);
    const int kxh = l + 64;
    const int kah = (l + 80) & 127;
    const int kbh = ((l + 64) & 0x70) | ((l + 66) & 15);

    float sq = 0.f, hAl = 0.f, hBl = 0.f, hAh = 0.f, hBh = 0.f;

    // ---- rows i = r .. r+56 : only low half valid (k <= i < 64) ----
    {
        int i = r;
        int o = (r * (r + 1)) >> 1;
        #pragma unroll 4
        for (int t = 0; t < 8; ++t) {
            const float* __restrict__ R = X + o;
            float x  = R[kxl];
            float a  = R[kal];
            float bb = R[kbl];
            x  = (kxl <= i) ? x  : 0.f;
            a  = (kal <= i) ? a  : 0.f;
            bb = (kbl <= i) ? bb : 0.f;
            sq  = fmaf(x, x,  sq);
            hAl = fmaf(x, a,  hAl);
            hBl = fmaf(x, bb, hBl);
            o += (i << 3) + 36;
            i += 8;
        }
    }
    // ---- rows i = r+64 .. r+120 : both halves ----
    {
        int i = r + 64;
        int o = (i * (i + 1)) >> 1;
        #pragma unroll 4
        for (int t = 0; t < 8; ++t) {
            const float* __restrict__ R = X + o;
            float x  = R[kxl];           // k=l <= 63 < i: always valid
            float a  = R[kal];
            float bb = R[kbl];
            a = (kal <= i) ? a : 0.f;    // kbl <= 63 < i: always valid
            sq  = fmaf(x, x,  sq);
            hAl = fmaf(x, a,  hAl);
            hBl = fmaf(x, bb, hBl);

            float xh = R[kxh];
            float ah = R[kah];
            float bh = R[kbh];
            xh = (kxh <= i) ? xh : 0.f;
            ah = (kah <= i) ? ah : 0.f;
            bh = (kbh <= i) ? bh : 0.f;
            sq  = fmaf(xh, xh, sq);
            hAh = fmaf(xh, ah, hAh);
            hBh = fmaf(xh, bh, hBh);

            o += (i << 3) + 36;
            i += 8;
        }
    }

    // per-lane coefficients (site of element k is k>>1); HW cos, rel err ~1e-5
    const float m2k = -2.0f * KAPPA;
    const float cAl = m2k * __cosf(U[(l >> 1)]);
    const float cAh = m2k * __cosf(U[32 + (l >> 1)]);
    const float cBl = m2k * __cosf(U[64 + (l >> 1)]);
    const float cBh = m2k * __cosf(U[96 + (l >> 1)]);

    float val = sq + cAl * hAl + cAh * hAh + cBl * hBl + cBh * hBh;

    // wave reduce
    #pragma unroll
    for (int off = 32; off > 0; off >>= 1)
        val += __shfl_down(val, off, 64);

    __shared__ float red[4];
    if (l == 0) red[w] = val;
    __syncthreads();

    // one plain (relaxed, no-fence) float atomic per block — R3-proven safe
    if (tid == 0)
        atomicAdd(out, (red[0] + red[1] + red[2] + red[3]) * SCALE);
}

extern "C" void kernel_launch(void* const* d_in, const int* in_sizes, int n_in,
                              void* d_out, int out_size, void* d_ws, size_t ws_size,
                              hipStream_t stream) {
    const float* net_out = (const float*)d_in[0];  // (1024, 8256) fp32
    const float* U1      = (const float*)d_in[1];  // (1024, 2, 8, 8) fp32
    float* out = (float*)d_out;                    // scalar fp32

    hipMemsetAsync(out, 0, sizeof(float), stream);
    trace_kernel<<<NBLK, 256, 0, stream>>>(net_out, U1, out);
}

// Round 11
// 13.647 us; speedup vs baseline: 10.2070x; 2.9990x over previous
//
#include <hip/hip_runtime.h>

#define KAPPA 0.276f
#define NTRI 8256        // 128*129/2 packed floats per batch
#define BATCH 1024
#define NBLK 2048        // 2 blocks per batch (row classes mod 8)
#define SCALE (1.0f / (128.0f * 1024.0f))   // /trace2(=128), /B for mean

// dst lane i <- src lane (i+2)&15 within each 16-lane row: row_ror:14 (0x12E).
// Implements B-partner kB(k) = (k&0x70)|((k+2)&15) on register data; applying
// it to the diagonal-masked own value also inherits the partner's mask.
__device__ __forceinline__ float rotl2(float v) {
    return __int_as_float(__builtin_amdgcn_mov_dpp(__float_as_int(v),
                                                   0x12E, 0xF, 0xF, false));
}

__global__ __launch_bounds__(256) void trace_kernel(const float* __restrict__ net_out,
                                                    const float* __restrict__ U1,
                                                    float* __restrict__ ws) {
    const int bid  = blockIdx.x;
    // XCD-aware swizzle: XCD x (dispatch round-robins bid&7) owns contiguous
    // batches [128x, 128x+128) -> ~4.2 MB working set, L2-resident per XCD.
    const int xcd  = bid & 7;
    const int slot = bid >> 3;                // 0..255 within XCD
    const int b    = (xcd << 7) + (slot >> 1);
    const int half = slot & 1;
    const int tid  = threadIdx.x;
    const int w    = tid >> 6;                // wave 0..3
    const int l    = tid & 63;                // lane owns elements k=l, k=l+64 per row
    const int r    = (half << 2) + w;         // row class 0..7: rows r, r+8, ..., r+120

    const float* __restrict__ X = net_out + (size_t)b * NTRI;
    const float* __restrict__ U = U1 + (size_t)b * 128;

    // per-lane coefficients (site of element k is k>>1); HW cos (rel err ~1e-5)
    const float m2k = -2.0f * KAPPA;
    const float cAl = m2k * __cosf(U[(l >> 1)]);
    const float cAh = m2k * __cosf(U[32 + (l >> 1)]);
    const float cBl = m2k * __cosf(U[64 + (l >> 1)]);
    const float cBh = m2k * __cosf(U[96 + (l >> 1)]);

    float sq = 0.f, hAl = 0.f, hBl = 0.f, hAh = 0.f, hBh = 0.f;

    // ---- rows i = r .. r+56 : only low half valid (k <= i < 64) ----
    {
        int i = r;
        int o = (r * (r + 1)) >> 1;
        #pragma unroll 4
        for (int t = 0; t < 8; ++t) {
            const float* __restrict__ R = X + o;
            float x = R[l];
            float a = R[l + 16];
            x = (l      <= i) ? x : 0.f;
            a = (l + 16 <= i) ? a : 0.f;
            float bb = rotl2(x);              // partner value+mask via DPP
            sq  = fmaf(x, x,  sq);
            hAl = fmaf(x, a,  hAl);
            hBl = fmaf(x, bb, hBl);
            o += (i << 3) + 36;               // tri(i+8)-tri(i)
            i += 8;
        }
    }
    // ---- rows i = r+64 .. r+120 : both halves ----
    {
        int i = r + 64;
        int o = (i * (i + 1)) >> 1;
        #pragma unroll 4
        for (int t = 0; t < 8; ++t) {
            const float* __restrict__ R = X + o;
            float x  = R[l];                  // k=l <= 63 < i: always valid
            float a  = R[l + 16];
            a = (l + 16 <= i) ? a : 0.f;
            float bb = rotl2(x);              // kbl <= 63 < i: always valid

            float xh = R[l + 64];
            xh = (l + 64 <= i) ? xh : 0.f;
            int kah  = (l + 80) & 127;
            float ah = R[kah];
            ah = (kah <= i) ? ah : 0.f;
            float bh = rotl2(xh);             // partner value+mask via DPP

            sq  = fmaf(x,  x,  sq);
            sq  = fmaf(xh, xh, sq);
            hAl = fmaf(x,  a,  hAl);
            hBl = fmaf(x,  bb, hBl);
            hAh = fmaf(xh, ah, hAh);
            hBh = fmaf(xh, bh, hBh);

            o += (i << 3) + 36;
            i += 8;
        }
    }

    float val = sq + cAl * hAl + cAh * hAh + cBl * hBl + cBh * hBh;

    // wave reduce
    #pragma unroll
    for (int off = 32; off > 0; off >>= 1)
        val += __shfl_down(val, off, 64);

    __shared__ float red[4];
    if (l == 0) red[w] = val;
    __syncthreads();
    if (tid == 0)
        ws[bid] = red[0] + red[1] + red[2] + red[3];
}

__global__ __launch_bounds__(256) void reduce_kernel(const float* __restrict__ ws,
                                                     float* __restrict__ out) {
    const int tid = threadIdx.x;
    float v = 0.f;
    #pragma unroll
    for (int m = 0; m < NBLK / 256; ++m)
        v += ws[tid + (m << 8)];
    #pragma unroll
    for (int off = 32; off > 0; off >>= 1)
        v += __shfl_down(v, off, 64);
    __shared__ float red[4];
    if ((tid & 63) == 0) red[tid >> 6] = v;
    __syncthreads();
    if (tid == 0)
        out[0] = (red[0] + red[1] + red[2] + red[3]) * SCALE;
}

extern "C" void kernel_launch(void* const* d_in, const int* in_sizes, int n_in,
                              void* d_out, int out_size, void* d_ws, size_t ws_size,
                              hipStream_t stream) {
    const float* net_out = (const float*)d_in[0];  // (1024, 8256) fp32
    const float* U1      = (const float*)d_in[1];  // (1024, 2, 8, 8) fp32
    float* out = (float*)d_out;                    // scalar fp32
    float* ws  = (float*)d_ws;                     // >= NBLK floats

    trace_kernel<<<NBLK, 256, 0, stream>>>(net_out, U1, ws);
    reduce_kernel<<<1, 256, 0, stream>>>(ws, out);
}

// Round 12
// 12.079 us; speedup vs baseline: 11.5327x; 1.1299x over previous
//
#include <hip/hip_runtime.h>

#define KAPPA 0.276f
#define NTRI 8256        // 128*129/2 packed floats per batch
#define BATCH 1024
#define NBLK 2048        // 2 blocks per batch (row classes mod 8)
#define SCALE (1.0f / (128.0f * 1024.0f))   // /trace2(=128), /B for mean

// dst lane i <- src lane (i+2)&15 within each 16-lane row: row_ror:14 (0x12E).
// Implements B-partner kB(k) = (k&0x70)|((k+2)&15) on register data; applying
// it to the diagonal-masked own value also inherits the partner's mask.
__device__ __forceinline__ float rotl2(float v) {
    return __int_as_float(__builtin_amdgcn_mov_dpp(__float_as_int(v),
                                                   0x12E, 0xF, 0xF, false));
}

__global__ __launch_bounds__(256) void trace_kernel(const float* __restrict__ net_out,
                                                    const float* __restrict__ U1,
                                                    float* __restrict__ ws) {
    const int bid  = blockIdx.x;
    // XCD-aware swizzle: XCD x (dispatch round-robins bid&7) owns contiguous
    // batches [128x, 128x+128) -> ~4.2 MB working set, L2-resident per XCD.
    const int xcd  = bid & 7;
    const int slot = bid >> 3;                // 0..255 within XCD
    const int b    = (xcd << 7) + (slot >> 1);
    const int half = slot & 1;
    const int tid  = threadIdx.x;
    const int w    = tid >> 6;                // wave 0..3
    const int l    = tid & 63;                // lane owns elements k=l, k=l+64 per row
    const int r    = (half << 2) + w;         // row class 0..7: rows r, r+8, ..., r+120

    const float* __restrict__ X = net_out + (size_t)b * NTRI;
    const float* __restrict__ U = U1 + (size_t)b * 128;

    // per-lane coefficients (site of element k is k>>1); HW cos (rel err ~1e-5)
    const float m2k = -2.0f * KAPPA;
    const float cAl = m2k * __cosf(U[(l >> 1)]);
    const float cAh = m2k * __cosf(U[32 + (l >> 1)]);
    const float cBl = m2k * __cosf(U[64 + (l >> 1)]);
    const float cBh = m2k * __cosf(U[96 + (l >> 1)]);

    const int  sidx = (l + 16) & 63;          // A-partner source lane (bpermute)
    const bool lo48 = (l < 48);

    float sq = 0.f, hAl = 0.f, hBl = 0.f, hAh = 0.f, hBh = 0.f;

    // ---- rows i = r .. r+56 : only low half valid (k <= i < 64) ----
    {
        int i = r;
        int o = (r * (r + 1)) >> 1;
        #pragma unroll 4
        for (int t = 0; t < 8; ++t) {
            const float* __restrict__ R = X + o;
            float x = R[l];
            x = (l <= i) ? x : 0.f;
            // A-partner: x of lane l+16 (mask inherited); zero for l>=48 (k+16 > i < 64)
            float ash = __shfl(x, sidx, 64);
            float a   = lo48 ? ash : 0.f;
            float bb  = rotl2(x);             // B-partner value+mask via DPP
            sq  = fmaf(x, x,  sq);
            hAl = fmaf(x, a,  hAl);
            hBl = fmaf(x, bb, hBl);
            o += (i << 3) + 36;               // tri(i+8)-tri(i)
            i += 8;
        }
    }
    // ---- rows i = r+64 .. r+120 : both halves ----
    {
        int i = r + 64;
        int o = (i * (i + 1)) >> 1;
        #pragma unroll 4
        for (int t = 0; t < 8; ++t) {
            const float* __restrict__ R = X + o;
            float x  = R[l];                  // k=l <= 63 < i: always valid
            float xh = R[l + 64];
            xh = (l + 64 <= i) ? xh : 0.f;

            // A-partners via 16-lane rotation of the (x, xh) register pair;
            // masks inherited exactly (lane algebra verified):
            //   a(l)  = l<48 ? x(l+16)  : xh(l-48)   [k_A = l+16]
            //   ah(l) = l<48 ? xh(l+16) : x(l-48)    [k_A = (l+80)&127]
            float sx  = __shfl(x,  sidx, 64);
            float sxh = __shfl(xh, sidx, 64);
            float a   = lo48 ? sx  : sxh;
            float ah  = lo48 ? sxh : sx;

            float bb = rotl2(x);              // always valid (kbl <= 63 < i)
            float bh = rotl2(xh);             // mask inherited

            sq  = fmaf(x,  x,  sq);
            sq  = fmaf(xh, xh, sq);
            hAl = fmaf(x,  a,  hAl);
            hBl = fmaf(x,  bb, hBl);
            hAh = fmaf(xh, ah, hAh);
            hBh = fmaf(xh, bh, hBh);

            o += (i << 3) + 36;
            i += 8;
        }
    }

    float val = sq + cAl * hAl + cAh * hAh + cBl * hBl + cBh * hBh;

    // wave reduce
    #pragma unroll
    for (int off = 32; off > 0; off >>= 1)
        val += __shfl_down(val, off, 64);

    __shared__ float red[4];
    if (l == 0) red[w] = val;
    __syncthreads();
    if (tid == 0)
        ws[bid] = red[0] + red[1] + red[2] + red[3];
}

__global__ __launch_bounds__(256) void reduce_kernel(const float* __restrict__ ws,
                                                     float* __restrict__ out) {
    const int tid = threadIdx.x;
    float v = 0.f;
    #pragma unroll
    for (int m = 0; m < NBLK / 256; ++m)
        v += ws[tid + (m << 8)];
    #pragma unroll
    for (int off = 32; off > 0; off >>= 1)
        v += __shfl_down(v, off, 64);
    __shared__ float red[4];
    if ((tid & 63) == 0) red[tid >> 6] = v;
    __syncthreads();
    if (tid == 0)
        out[0] = (red[0] + red[1] + red[2] + red[3]) * SCALE;
}

extern "C" void kernel_launch(void* const* d_in, const int* in_sizes, int n_in,
                              void* d_out, int out_size, void* d_ws, size_t ws_size,
                              hipStream_t stream) {
    const float* net_out = (const float*)d_in[0];  // (1024, 8256) fp32
    const float* U1      = (const float*)d_in[1];  // (1024, 2, 8, 8) fp32
    float* out = (float*)d_out;                    // scalar fp32
    float* ws  = (float*)d_ws;                     // >= NBLK floats

    trace_kernel<<<NBLK, 256, 0, stream>>>(net_out, U1, ws);
    reduce_kernel<<<1, 256, 0, stream>>>(ws, out);
}